// Round 20
// baseline (157.123 us; speedup 1.0000x reference)
//
#include <hip/hip_runtime.h>
#include <stdint.h>

typedef unsigned short u16;
typedef __bf16 bf16x8 __attribute__((ext_vector_type(8)));
typedef short  short8 __attribute__((ext_vector_type(8)));
typedef float  f32x4  __attribute__((ext_vector_type(4)));
typedef float  float4v __attribute__((ext_vector_type(4)));
typedef uint32_t u32x2 __attribute__((ext_vector_type(2)));

#define NG    32
#define NPG   512
#define HIDD  512
#define NH    8
#define HD    64
#define NE    262144
#define NNODE (NG*NPG)

__device__ __forceinline__ float fexp2(float x) { return __builtin_amdgcn_exp2f(x); }

__device__ __forceinline__ u16 f2bf(float f) {
  union { float f; uint32_t u; } x; x.f = f;
  uint32_t r = x.u + 0x7FFFu + ((x.u >> 16) & 1u);
  return (u16)(r >> 16);
}
__device__ __forceinline__ float bf2f(u16 b) {
  union { uint32_t u; float f; } x; x.u = ((uint32_t)b) << 16;
  return x.f;
}
// native casts -> compiler emits v_cvt_pk_bf16_f32 for pairs
__device__ __forceinline__ uint32_t pkbf(float a, float b) {
  __bf16 x = (__bf16)a, y = (__bf16)b;
  return (uint32_t)__builtin_bit_cast(u16, x) | ((uint32_t)__builtin_bit_cast(u16, y) << 16);
}
__device__ __forceinline__ bf16x8 ldfrag(const u16* p) {
  short8 t = *(const short8*)p;
  return __builtin_bit_cast(bf16x8, t);
}
__device__ __forceinline__ f32x4 mfma16(bf16x8 a, bf16x8 b, f32x4 c) {
  return __builtin_amdgcn_mfma_f32_16x16x32_bf16(a, b, c, 0, 0, 0);
}
__device__ __forceinline__ void gl2lds16(const void* g, void* l) {
  __builtin_amdgcn_global_load_lds((const __attribute__((address_space(1))) void*)g,
                                   (__attribute__((address_space(3))) void*)l, 16, 0, 0);
}
__device__ __forceinline__ void st(u16* p, float v)   { *p = f2bf(v); }
__device__ __forceinline__ void st(float* p, float v) { *p = v; }

// ---------------- fused prep: cast_x [0,4096) | transw [4096,5120) | count2 [5120,6144) ----

__global__ void k_prep(const float* __restrict__ x, u16* __restrict__ xb,
                       const float* __restrict__ W0, const float* __restrict__ W1,
                       const float* __restrict__ W2, const float* __restrict__ W3,
                       u16* __restrict__ wt,
                       const int* __restrict__ ei, int* __restrict__ counts) {
  __shared__ float tl[32][33];
  const int bid = blockIdx.x, t = threadIdx.x;
  if (bid < 4096) {
    size_t i = ((size_t)bid * 256 + t) * 8;
    float4v v0 = *(const float4v*)(x + i);
    float4v v1 = *(const float4v*)(x + i + 4);
    short8 r;
    r[0]=(short)f2bf(v0[0]); r[1]=(short)f2bf(v0[1]); r[2]=(short)f2bf(v0[2]); r[3]=(short)f2bf(v0[3]);
    r[4]=(short)f2bf(v1[0]); r[5]=(short)f2bf(v1[1]); r[6]=(short)f2bf(v1[2]); r[7]=(short)f2bf(v1[3]);
    *(short8*)(xb + i) = r;
  } else if (bid < 5120) {
    const int id2 = bid - 4096;
    const int z = id2 >> 8, rem = id2 & 255;
    const int y0 = (rem >> 4) * 32, x0 = (rem & 15) * 32;
    const float* W = z==0 ? W0 : z==1 ? W1 : z==2 ? W2 : W3;
    u16* out = wt + (size_t)z * HIDD * HIDD;
    const int tx = t & 31, ty = t >> 5;
    #pragma unroll
    for (int i = 0; i < 4; ++i) tl[ty + i*8][tx] = W[(size_t)(y0 + ty + i*8) * HIDD + x0 + tx];
    __syncthreads();
    #pragma unroll
    for (int i = 0; i < 4; ++i) out[(size_t)(x0 + ty + i*8) * HIDD + (y0 + tx)] = f2bf(tl[tx][ty + i*8]);
  } else {
    int e = (bid - 5120) * 256 + t;
    int src = ei[e];
    int dl  = ei[NE + e] & (NPG - 1);
    atomicAdd(&counts[src * 8 + (dl >> 6)], 1);
  }
}

// ---------------- unordered scan -> rowstart[] (fill cursor) + rowse[] = end<<7|cnt ----

__global__ void k_scan_u(const int* __restrict__ counts, int* __restrict__ rowstart,
                         uint32_t* __restrict__ rowse, int* __restrict__ gcur) {
  __shared__ int arr[256];
  __shared__ int basesh;
  const int t = threadIdx.x;
  const int i = blockIdx.x * 256 + t;
  const int c = counts[i];
  arr[t] = c;
  __syncthreads();
  for (int off = 1; off < 256; off <<= 1) {
    int v = (t >= off) ? arr[t - off] : 0;
    __syncthreads();
    arr[t] += v;
    __syncthreads();
  }
  const int incl = arr[t];
  if (t == 255) basesh = atomicAdd(gcur, incl);   // incl@255 == block total
  __syncthreads();
  const int end = basesh + incl;
  rowstart[i] = end - c;                          // consumed (destroyed) by k_mid fill
  rowse[i] = ((uint32_t)end << 7) | (uint32_t)(c & 127u);  // cnt<=~15 (Poisson mean 2)
}

// ---------------- GEMM body (128x128, BK=32, 2-buffer, R2-measured loop) ----------------
// R19 layout kept: row-major tiles, within-row chunk permutation jd = g ^ ((row>>1)&3)
// (coalesced sources + conflict-floor frag reads). R20: min-waves bound 3 -> 4.

template <typename OT, bool VOUT>
__device__ void gemm_body(u16* smem, int idl, const u16* __restrict__ A,
                          const u16* __restrict__ Bt, const float* __restrict__ bias,
                          OT* __restrict__ C, u16* __restrict__ vtg, float oscale) {
  const int tid = threadIdx.x;
  const int w = tid >> 6, l = tid & 63, lr = l & 15, lg = l >> 4;
  const int nid = (idl & 7) * 64 + (idl >> 3);          // bijective XCD remap
  const int bn0 = (nid & 3) * 128, bm0 = (nid >> 2) * 128;
  const int wr = w >> 1, wc = w & 1;
  f32x4 acc[4][4];
  #pragma unroll
  for (int i = 0; i < 4; ++i)
    #pragma unroll
    for (int j = 0; j < 4; ++j) acc[i][j] = (f32x4){0.f, 0.f, 0.f, 0.f};

  const int o1 = w * 1024 + l * 16;
  auto stageAB = [&](int kt, int buf) {
    #pragma unroll
    for (int rnd = 0; rnd < 2; ++rnd) {
      const int o = rnd * 4096 + o1;
      const int row = o >> 6, jd = (o >> 4) & 3;
      const int g = jd ^ ((row >> 1) & 3);     // source chunk within same 64B row
      gl2lds16((const char*)A  + ((size_t)(bm0 + row) * HIDD + kt * 32 + g * 8) * 2,
               (char*)smem + buf * 8192 + o);
      gl2lds16((const char*)Bt + ((size_t)(bn0 + row) * HIDD + kt * 32 + g * 8) * 2,
               (char*)smem + 16384 + buf * 8192 + o);
    }
  };

  const int sA = (lg ^ ((lr >> 1) & 3)) * 8;   // frag slot offset (u16) within row

  stageAB(0, 0);
  for (int kt = 0; kt < 16; ++kt) {
    if (kt < 15) {
      stageAB(kt + 1, (kt + 1) & 1);
      asm volatile("s_waitcnt vmcnt(4)" ::: "memory");
    } else {
      asm volatile("s_waitcnt vmcnt(0)" ::: "memory");
    }
    __syncthreads();
    const u16* Ab = smem + (kt & 1) * 4096;
    const u16* Bb = smem + 8192 + (kt & 1) * 4096;
    bf16x8 af[4], bfr[4];
    #pragma unroll
    for (int i = 0; i < 4; ++i) af[i]  = ldfrag(&Ab[(wr*64 + i*16 + lr) * 32 + sA]);
    #pragma unroll
    for (int j = 0; j < 4; ++j) bfr[j] = ldfrag(&Bb[(wc*64 + j*16 + lr) * 32 + sA]);
    #pragma unroll
    for (int i = 0; i < 4; ++i)
      #pragma unroll
      for (int j = 0; j < 4; ++j)
        acc[i][j] = mfma16(af[i], bfr[j], acc[i][j]);
    __syncthreads();
  }

  if constexpr (VOUT) {
    #pragma unroll
    for (int j = 0; j < 4; ++j) {
      const int d = j * 16 + lr;
      const float bv = bias[bn0 + wc*64 + j*16 + lr];
      #pragma unroll
      for (int i = 0; i < 4; ++i) {
        const int t4 = wc * 2 + wr;
        const int byteo = t4 * 8192 + d * 128 + ((i*32 + lg*8) ^ ((d & 7) << 4));
        uint32_t lo = pkbf(acc[i][j][0] + bv, acc[i][j][1] + bv);
        uint32_t hi = pkbf(acc[i][j][2] + bv, acc[i][j][3] + bv);
        *(u32x2*)((char*)smem + byteo) = (u32x2){lo, hi};
      }
    }
    __syncthreads();
    const int b = bm0 >> 9, kt0 = (bm0 & 511) >> 6, h0 = bn0 >> 6;
    #pragma unroll
    for (int t4 = 0; t4 < 4; ++t4) {
      size_t base = ((size_t)(b * 8 + h0 + (t4 >> 1)) * 8 + kt0 + (t4 & 1)) * 4096;
      #pragma unroll
      for (int rnd = 0; rnd < 2; ++rnd) {
        int idx = rnd * 256 + tid;
        *(short8*)(vtg + base + idx * 8) = *(const short8*)&smem[t4 * 4096 + idx * 8];
      }
    }
  } else {
    #pragma unroll
    for (int j = 0; j < 4; ++j) {
      const int col = bn0 + wc*64 + j*16 + lr;
      const float bv = bias[col];
      #pragma unroll
      for (int i = 0; i < 4; ++i) {
        const int row0 = bm0 + wr*64 + i*16 + lg*4;
        #pragma unroll
        for (int q = 0; q < 4; ++q)
          st(&C[(size_t)(row0 + q) * HIDD + col], (acc[i][j][q] + bv) * oscale);
      }
    }
  }
}

// ---------------- k_mid: fill [0,1024) || QKV GEMM [1024,2560) (independent work) ----

__global__ __launch_bounds__(256, 4) void k_mid(
    const int* __restrict__ ei, const float* __restrict__ ea,
    const float* __restrict__ We, const float* __restrict__ be,
    int* __restrict__ rowcur, uint32_t* __restrict__ packed,
    const u16* __restrict__ A, const u16* __restrict__ Wt,
    const float* __restrict__ b0, const float* __restrict__ b1, const float* __restrict__ b2,
    u16* __restrict__ O0, u16* __restrict__ O1, u16* __restrict__ vtg) {
  __shared__ u16 smem[16384];   // 32KB (gemm); fill path carves 544B for We/be
  const int bid = blockIdx.x, t = threadIdx.x;
  if (bid < 1024) {
    float* w  = (float*)smem;        // 128 floats
    float* bb = (float*)smem + 128;  // 8 floats
    if (t < 128) w[t] = We[t];
    if (t < 8)   bb[t] = be[t];
    __syncthreads();
    int e = bid * 256 + t;
    int src = ei[e];
    int dl  = ei[NE + e] & (NPG - 1);
    const float* ap = ea + (size_t)e * 16;
    float a[16];
    #pragma unroll
    for (int i = 0; i < 16; i += 4) {
      float4v v = *(const float4v*)(ap + i);
      a[i]=v[0]; a[i+1]=v[1]; a[i+2]=v[2]; a[i+3]=v[3];
    }
    float acc[8];
    #pragma unroll
    for (int hh = 0; hh < 8; ++hh) acc[hh] = bb[hh];
    #pragma unroll
    for (int d = 0; d < 16; ++d)
      #pragma unroll
      for (int hh = 0; hh < 8; ++hh) acc[hh] += a[d] * w[d*8 + hh];
    int bin = src * 8 + (dl >> 6);
    int slot = atomicAdd(&rowcur[bin], 1);
    size_t base = (size_t)slot * 8;
    #pragma unroll
    for (int hh = 0; hh < 8; ++hh) {
      float m = fexp2(acc[hh] * 1.44269504089f);
      union { _Float16 hf; u16 us; } cv; cv.hf = (_Float16)m;
      packed[base + hh] = (uint32_t)(dl & 63) | ((uint32_t)cv.us << 16);
    }
  } else {
    const int idx = bid - 1024;
    const int z = idx >> 9, idl = idx & 511;
    const float c1 = 0.125f * 1.44269504089f;  // softmax scale folded into Q
    const u16* Bt = Wt + (size_t)z * HIDD * HIDD;
    if (z == 0)      gemm_body<u16, false>(smem, idl, A, Bt, b0, O0, nullptr, c1);
    else if (z == 1) gemm_body<u16, false>(smem, idl, A, Bt, b1, O1, nullptr, 1.0f);
    else             gemm_body<u16, true >(smem, idl, A, Bt, b2, nullptr, vtg, 1.0f);
  }
}

__global__ __launch_bounds__(256, 4) void k_gemm_out(
    const u16* __restrict__ A, const u16* __restrict__ Bt,
    const float* __restrict__ bias, float* __restrict__ C) {
  __shared__ u16 smem[16384];
  gemm_body<float, false>(smem, blockIdx.x + (blockIdx.y << 2), A, Bt, bias, C,
                          nullptr, 1.0f);
}

// ---------------- fused attention (R17 body, unchanged) ----------------

__global__ __launch_bounds__(256, 4) void k_attn(
    const u16* __restrict__ qb, const u16* __restrict__ kb, const u16* __restrict__ vtg,
    const uint32_t* __restrict__ packed, const uint32_t* __restrict__ rowse,
    u16* __restrict__ ab) {
  __shared__ u16 kl[4096];      // 8KB K tile [64 key][128B] swizzled
  __shared__ u16 vl[4096];      // 8KB V^T tile [64 d][128B] swizzled
  __shared__ u16 pl[4][2048];   // 16KB per-wave P tiles [32 row][64 key] swizzled
  const int tid = threadIdx.x, w = tid >> 6, l = tid & 63, lr = l & 15, lg = l >> 4;

  const int id = blockIdx.x;
  const int nid = (id & 7) * 128 + (id >> 3);   // XCD-contiguous (1024 % 8 == 0)
  const int q0 = (nid & 3) * 128;
  const int h  = (nid >> 2) & 7;
  const int b  = nid >> 5;
  const int bh = b * 8 + h;
  const int rbase = q0 + w * 32;                // wave's first q-row within graph
  u16* plw = &pl[w][0];
  const int pswz = (lr & 7) << 4;               // (g*16+lr)&7 == lr&7: group-invariant

  // Q fragments for both row groups
  bf16x8 qf[2][2];
  #pragma unroll
  for (int g = 0; g < 2; ++g) {
    const u16* qp = qb + (size_t)(b * NPG + rbase + g * 16 + lr) * HIDD + h * HD + lg * 8;
    qf[g][0] = ldfrag(qp);
    qf[g][1] = ldfrag(qp + 32);
  }

  auto stageK = [&](int kt) {
    #pragma unroll
    for (int rnd = 0; rnd < 2; ++rnd) {
      int o = rnd * 4096 + w * 1024 + l * 16;
      int key = o >> 7, db = o & 127;
      int col = db ^ ((key & 7) << 4);
      gl2lds16((const char*)kb + ((size_t)(b * NPG + kt * 64 + key) * HIDD + h * HD) * 2 + col,
               (char*)kl + o);
    }
  };
  auto stageV = [&](int kt) {
    #pragma unroll
    for (int rnd = 0; rnd < 2; ++rnd) {
      int o = rnd * 4096 + w * 1024 + l * 16;
      gl2lds16((const char*)vtg + ((size_t)(bh * 8 + kt)) * 8192 + o,
               (char*)vl + o);
    }
  };

  float rs[2] = {0.f, 0.f};
  f32x4 oacc[2][4];
  #pragma unroll
  for (int g = 0; g < 2; ++g)
    #pragma unroll
    for (int dt = 0; dt < 4; ++dt) oacc[g][dt] = (f32x4){0.f, 0.f, 0.f, 0.f};

  stageK(0); stageV(0);

  // per-lane edge row: group ge = lg&1, dst-parity class = lg>>1
  const int ge = lg & 1, ecls = lg >> 1;
  const int egrow = b * NPG + rbase + ge * 16 + lr;
  uint32_t ub = rowse[egrow * 8];
  int eE = (int)(ub >> 7), eA = eE - (int)(ub & 127u);

  for (int kt = 0; kt < 8; ++kt) {
    asm volatile("s_waitcnt vmcnt(0)" ::: "memory");   // K(kt), V(kt) landed
    __syncthreads();

    // prefetch next tile's packed bounds + this tile's first edge entry (fly under QK^T)
    uint32_t uN = (kt < 7) ? rowse[egrow * 8 + kt + 1] : 0;
    int s0c = (eA < eE) ? eA : 0;
    uint32_t u0 = packed[(size_t)s0c * 8 + h];

    // QK^T (swapped): s4[g][sub][e] = S[key = kt*64 + sub*16 + lg*4 + e][rbase+g*16+lr]
    f32x4 s4[2][4];
    __builtin_amdgcn_s_setprio(1);
    #pragma unroll
    for (int sub = 0; sub < 4; ++sub) {
      int key = sub * 16 + lr;
      bf16x8 kf0, kf1;
      {
        int db0 = ((lg * 8) * 2) ^ ((key & 7) << 4);
        int db1 = ((32 + lg * 8) * 2) ^ ((key & 7) << 4);
        kf0 = ldfrag(&kl[(key * 128 + db0) >> 1]);
        kf1 = ldfrag(&kl[(key * 128 + db1) >> 1]);
      }
      #pragma unroll
      for (int g = 0; g < 2; ++g) {
        s4[g][sub] = mfma16(kf0, qf[g][0], (f32x4){0.f, 0.f, 0.f, 0.f});
        s4[g][sub] = mfma16(kf1, qf[g][1], s4[g][sub]);
      }
    }
    __builtin_amdgcn_s_setprio(0);

    // p = exp2(S) (Q pre-scaled) -> per-wave LDS P tile; rowsums in regs
    #pragma unroll
    for (int g = 0; g < 2; ++g) {
      const int prow = g * 16 + lr;
      #pragma unroll
      for (int sub = 0; sub < 4; ++sub) {
        float p0 = fexp2(s4[g][sub][0]);
        float p1 = fexp2(s4[g][sub][1]);
        float p2 = fexp2(s4[g][sub][2]);
        float p3 = fexp2(s4[g][sub][3]);
        rs[g] += (p0 + p1) + (p2 + p3);
        uint32_t lo = pkbf(p0, p1);
        uint32_t hi = pkbf(p2, p3);
        *(u32x2*)((char*)plw + prow * 128 + ((sub * 32 + lg * 8) ^ pswz)) = (u32x2){lo, hi};
      }
    }
    asm volatile("s_waitcnt lgkmcnt(0)" ::: "memory");
    __builtin_amdgcn_sched_barrier(0);

    // edge multipliers: 2 lanes/row (dst parity classes), 1-ahead load pipeline
    {
      float delta = 0.f;
      const int re = ge * 16 + lr;
      uint32_t u = u0;
      for (int s = eA; s < eE; ++s) {
        uint32_t ucur = u;
        if (s + 1 < eE) u = packed[(size_t)(s + 1) * 8 + h];
        int dl = (int)(ucur & 63u);
        if ((dl & 1) == ecls) {
          union { u16 us; _Float16 hf; } cv; cv.us = (u16)(ucur >> 16);
          float mult = (float)cv.hf;
          int idx = (re * 128 + ((dl * 2) ^ pswz)) >> 1;
          float old = bf2f(plw[idx]);
          plw[idx] = f2bf(old * mult);
          delta += old * (mult - 1.0f);
        }
      }
      rs[0] += (ge == 0) ? delta : 0.f;
      rs[1] += (ge == 1) ? delta : 0.f;
    }
    asm volatile("s_waitcnt lgkmcnt(0)" ::: "memory");
    __builtin_amdgcn_sched_barrier(0);

    // PV: vf frags read once, used for both row groups
    __builtin_amdgcn_s_setprio(1);
    #pragma unroll
    for (int ks = 0; ks < 2; ++ks) {
      bf16x8 pa0 = ldfrag(&plw[(lr * 128 + ((ks * 64 + lg * 16) ^ pswz)) >> 1]);
      bf16x8 pa1 = ldfrag(&plw[((16 + lr) * 128 + ((ks * 64 + lg * 16) ^ pswz)) >> 1]);
      #pragma unroll
      for (int dt = 0; dt < 4; ++dt) {
        int d = dt * 16 + lr;
        bf16x8 vf = ldfrag(&vl[(d * 128 + ((ks * 64 + lg * 16) ^ ((d & 7) << 4))) >> 1]);
        oacc[0][dt] = mfma16(vf, pa0, oacc[0][dt]);
        oacc[1][dt] = mfma16(vf, pa1, oacc[1][dt]);
      }
    }
    __builtin_amdgcn_s_setprio(0);

    __syncthreads();   // all waves done reading kl/vl -> safe to restage
    if (kt < 7) { stageK(kt + 1); stageV(kt + 1); }
    eE = (int)(uN >> 7); eA = eE - (int)(uN & 127u);
  }

  // reduce rowsums across lg, normalize, store O (packed 8B per dt per group)
  #pragma unroll
  for (int g = 0; g < 2; ++g) {
    float tot = rs[g] + __shfl_xor(rs[g], 16, 64);
    tot += __shfl_xor(tot, 32, 64);
    float inv = 1.0f / tot;
    const size_t grow = (size_t)(b * NPG + rbase + g * 16 + lr);
    #pragma unroll
    for (int dt = 0; dt < 4; ++dt) {
      uint32_t lo = pkbf(oacc[g][dt][0] * inv, oacc[g][dt][1] * inv);
      uint32_t hi = pkbf(oacc[g][dt][2] * inv, oacc[g][dt][3] * inv);
      *(u32x2*)(ab + grow * HIDD + h * HD + dt * 16 + lg * 4) = (u32x2){lo, hi};
    }
  }
}

// ---------------- launch ----------------

extern "C" void kernel_launch(void* const* d_in, const int* in_sizes, int n_in,
                              void* d_out, int out_size, void* d_ws, size_t ws_size,
                              hipStream_t stream) {
  const float* x  = (const float*)d_in[0];
  const int*   ei = (const int*)d_in[2];
  const float* ea = (const float*)d_in[3];
  const float* Wq = (const float*)d_in[4];  const float* bq = (const float*)d_in[5];
  const float* Wk = (const float*)d_in[6];  const float* bk = (const float*)d_in[7];
  const float* Wv = (const float*)d_in[8];  const float* bv = (const float*)d_in[9];
  const float* Wo = (const float*)d_in[10]; const float* bo = (const float*)d_in[11];
  const float* We = (const float*)d_in[12]; const float* be = (const float*)d_in[13];

  char* ws = (char*)d_ws;
  const size_t MB = 1 << 20;
  u16*  xb  = (u16*)(ws);             // 16 MiB (aliased as ab after QKV GEMM)
  u16*  wt  = (u16*)(ws + 16*MB);     // 2 MiB
  u16*  qbp = (u16*)(ws + 18*MB);     // 16 MiB
  u16*  kbp = (u16*)(ws + 34*MB);     // 16 MiB
  u16*  vtg = (u16*)(ws + 50*MB);     // 16 MiB  V^T tiled/swizzled [bh][8][4096]
  uint32_t* packed = (uint32_t*)(ws + 66*MB);        // 8 MiB
  int*      rowstart2 = (int*)(ws + 74*MB);          // 512 KiB (scan -> fill cursor)
  uint32_t* rowse     = (uint32_t*)(ws + 74*MB + 640*1024);  // 512 KiB (end<<7|cnt)
  // counts2/gcur overlap the vtg region: dead before k_mid writes vtg
  int*  counts2 = (int*)(ws + 50*MB);                // 512 KiB
  int*  gcur    = (int*)(ws + 50*MB + 512*1024);     // 4 B
  u16*  ab = xb;

  (void)hipMemsetAsync(counts2, 0, 512 * 1024 + 64, stream);  // counts2 + gcur

  k_prep<<<dim3(6144), 256, 0, stream>>>(x, xb, Wq, Wk, Wv, Wo, wt, ei, counts2);
  k_scan_u<<<dim3(512), 256, 0, stream>>>(counts2, rowstart2, rowse, gcur);

  k_mid<<<dim3(2560), 256, 0, stream>>>(ei, ea, We, be, rowstart2, packed,
                                        xb, wt, bq, bk, bv, qbp, kbp, vtg);

  k_attn<<<dim3(1024), 256, 0, stream>>>(qbp, kbp, vtg, packed, rowse, ab);

  k_gemm_out<<<dim3(HIDD / 128, NNODE / 128, 1), 256, 0, stream>>>(
      ab, wt + (size_t)3 * HIDD * HIDD, bo, (float*)d_out);
}

// Round 21
// 150.291 us; speedup vs baseline: 1.0455x; 1.0455x over previous
//
#include <hip/hip_runtime.h>
#include <stdint.h>

typedef unsigned short u16;
typedef __bf16 bf16x8 __attribute__((ext_vector_type(8)));
typedef short  short8 __attribute__((ext_vector_type(8)));
typedef float  f32x4  __attribute__((ext_vector_type(4)));
typedef float  float4v __attribute__((ext_vector_type(4)));
typedef uint32_t u32x2 __attribute__((ext_vector_type(2)));

#define NG    32
#define NPG   512
#define HIDD  512
#define NH    8
#define HD    64
#define NE    262144
#define NNODE (NG*NPG)

__device__ __forceinline__ float fexp2(float x) { return __builtin_amdgcn_exp2f(x); }

__device__ __forceinline__ u16 f2bf(float f) {
  union { float f; uint32_t u; } x; x.f = f;
  uint32_t r = x.u + 0x7FFFu + ((x.u >> 16) & 1u);
  return (u16)(r >> 16);
}
__device__ __forceinline__ float bf2f(u16 b) {
  union { uint32_t u; float f; } x; x.u = ((uint32_t)b) << 16;
  return x.f;
}
// native casts -> compiler emits v_cvt_pk_bf16_f32 for pairs
__device__ __forceinline__ uint32_t pkbf(float a, float b) {
  __bf16 x = (__bf16)a, y = (__bf16)b;
  return (uint32_t)__builtin_bit_cast(u16, x) | ((uint32_t)__builtin_bit_cast(u16, y) << 16);
}
__device__ __forceinline__ bf16x8 ldfrag(const u16* p) {
  short8 t = *(const short8*)p;
  return __builtin_bit_cast(bf16x8, t);
}
__device__ __forceinline__ f32x4 mfma16(bf16x8 a, bf16x8 b, f32x4 c) {
  return __builtin_amdgcn_mfma_f32_16x16x32_bf16(a, b, c, 0, 0, 0);
}
__device__ __forceinline__ void gl2lds16(const void* g, void* l) {
  __builtin_amdgcn_global_load_lds((const __attribute__((address_space(1))) void*)g,
                                   (__attribute__((address_space(3))) void*)l, 16, 0, 0);
}
__device__ __forceinline__ void st(u16* p, float v)   { *p = f2bf(v); }
__device__ __forceinline__ void st(float* p, float v) { *p = v; }

// ---------------- fused prep: cast_x [0,4096) | transw [4096,5120) | count2 [5120,6144) ----

__global__ void k_prep(const float* __restrict__ x, u16* __restrict__ xb,
                       const float* __restrict__ W0, const float* __restrict__ W1,
                       const float* __restrict__ W2, const float* __restrict__ W3,
                       u16* __restrict__ wt,
                       const int* __restrict__ ei, int* __restrict__ counts) {
  __shared__ float tl[32][33];
  const int bid = blockIdx.x, t = threadIdx.x;
  if (bid < 4096) {
    size_t i = ((size_t)bid * 256 + t) * 8;
    float4v v0 = *(const float4v*)(x + i);
    float4v v1 = *(const float4v*)(x + i + 4);
    short8 r;
    r[0]=(short)f2bf(v0[0]); r[1]=(short)f2bf(v0[1]); r[2]=(short)f2bf(v0[2]); r[3]=(short)f2bf(v0[3]);
    r[4]=(short)f2bf(v1[0]); r[5]=(short)f2bf(v1[1]); r[6]=(short)f2bf(v1[2]); r[7]=(short)f2bf(v1[3]);
    *(short8*)(xb + i) = r;
  } else if (bid < 5120) {
    const int id2 = bid - 4096;
    const int z = id2 >> 8, rem = id2 & 255;
    const int y0 = (rem >> 4) * 32, x0 = (rem & 15) * 32;
    const float* W = z==0 ? W0 : z==1 ? W1 : z==2 ? W2 : W3;
    u16* out = wt + (size_t)z * HIDD * HIDD;
    const int tx = t & 31, ty = t >> 5;
    #pragma unroll
    for (int i = 0; i < 4; ++i) tl[ty + i*8][tx] = W[(size_t)(y0 + ty + i*8) * HIDD + x0 + tx];
    __syncthreads();
    #pragma unroll
    for (int i = 0; i < 4; ++i) out[(size_t)(x0 + ty + i*8) * HIDD + (y0 + tx)] = f2bf(tl[tx][ty + i*8]);
  } else {
    int e = (bid - 5120) * 256 + t;
    int src = ei[e];
    int dl  = ei[NE + e] & (NPG - 1);
    atomicAdd(&counts[src * 8 + (dl >> 6)], 1);
  }
}

// ---------------- unordered scan -> rowstart[] (fill cursor) + rowse[] = end<<7|cnt ----

__global__ void k_scan_u(const int* __restrict__ counts, int* __restrict__ rowstart,
                         uint32_t* __restrict__ rowse, int* __restrict__ gcur) {
  __shared__ int arr[256];
  __shared__ int basesh;
  const int t = threadIdx.x;
  const int i = blockIdx.x * 256 + t;
  const int c = counts[i];
  arr[t] = c;
  __syncthreads();
  for (int off = 1; off < 256; off <<= 1) {
    int v = (t >= off) ? arr[t - off] : 0;
    __syncthreads();
    arr[t] += v;
    __syncthreads();
  }
  const int incl = arr[t];
  if (t == 255) basesh = atomicAdd(gcur, incl);   // incl@255 == block total
  __syncthreads();
  const int end = basesh + incl;
  rowstart[i] = end - c;                          // consumed (destroyed) by k_mid fill
  rowse[i] = ((uint32_t)end << 7) | (uint32_t)(c & 127u);  // cnt<=~15 (Poisson mean 2)
}

// ---------------- GEMM body (128x128, BK=32, 2-buffer, R2-measured loop) ----------------
// R19 layout: row-major tiles, within-row chunk permutation jd = g ^ ((row>>1)&3)
// (coalesced sources + conflict-floor frag reads). Bound stays (256,3): R20's (256,4)
// clamped VGPR 84->60 and spilled (+31MB scratch writes) -- 3rd confirmation of the
// register cliff just above 3 blocks/CU for this body.

template <typename OT, bool VOUT>
__device__ void gemm_body(u16* smem, int idl, const u16* __restrict__ A,
                          const u16* __restrict__ Bt, const float* __restrict__ bias,
                          OT* __restrict__ C, u16* __restrict__ vtg, float oscale) {
  const int tid = threadIdx.x;
  const int w = tid >> 6, l = tid & 63, lr = l & 15, lg = l >> 4;
  const int nid = (idl & 7) * 64 + (idl >> 3);          // bijective XCD remap
  const int bn0 = (nid & 3) * 128, bm0 = (nid >> 2) * 128;
  const int wr = w >> 1, wc = w & 1;
  f32x4 acc[4][4];
  #pragma unroll
  for (int i = 0; i < 4; ++i)
    #pragma unroll
    for (int j = 0; j < 4; ++j) acc[i][j] = (f32x4){0.f, 0.f, 0.f, 0.f};

  const int o1 = w * 1024 + l * 16;
  auto stageAB = [&](int kt, int buf) {
    #pragma unroll
    for (int rnd = 0; rnd < 2; ++rnd) {
      const int o = rnd * 4096 + o1;
      const int row = o >> 6, jd = (o >> 4) & 3;
      const int g = jd ^ ((row >> 1) & 3);     // source chunk within same 64B row
      gl2lds16((const char*)A  + ((size_t)(bm0 + row) * HIDD + kt * 32 + g * 8) * 2,
               (char*)smem + buf * 8192 + o);
      gl2lds16((const char*)Bt + ((size_t)(bn0 + row) * HIDD + kt * 32 + g * 8) * 2,
               (char*)smem + 16384 + buf * 8192 + o);
    }
  };

  const int sA = (lg ^ ((lr >> 1) & 3)) * 8;   // frag slot offset (u16) within row

  stageAB(0, 0);
  for (int kt = 0; kt < 16; ++kt) {
    if (kt < 15) {
      stageAB(kt + 1, (kt + 1) & 1);
      asm volatile("s_waitcnt vmcnt(4)" ::: "memory");
    } else {
      asm volatile("s_waitcnt vmcnt(0)" ::: "memory");
    }
    __syncthreads();
    const u16* Ab = smem + (kt & 1) * 4096;
    const u16* Bb = smem + 8192 + (kt & 1) * 4096;
    bf16x8 af[4], bfr[4];
    #pragma unroll
    for (int i = 0; i < 4; ++i) af[i]  = ldfrag(&Ab[(wr*64 + i*16 + lr) * 32 + sA]);
    #pragma unroll
    for (int j = 0; j < 4; ++j) bfr[j] = ldfrag(&Bb[(wc*64 + j*16 + lr) * 32 + sA]);
    #pragma unroll
    for (int i = 0; i < 4; ++i)
      #pragma unroll
      for (int j = 0; j < 4; ++j)
        acc[i][j] = mfma16(af[i], bfr[j], acc[i][j]);
    __syncthreads();
  }

  if constexpr (VOUT) {
    #pragma unroll
    for (int j = 0; j < 4; ++j) {
      const int d = j * 16 + lr;
      const float bv = bias[bn0 + wc*64 + j*16 + lr];
      #pragma unroll
      for (int i = 0; i < 4; ++i) {
        const int t4 = wc * 2 + wr;
        const int byteo = t4 * 8192 + d * 128 + ((i*32 + lg*8) ^ ((d & 7) << 4));
        uint32_t lo = pkbf(acc[i][j][0] + bv, acc[i][j][1] + bv);
        uint32_t hi = pkbf(acc[i][j][2] + bv, acc[i][j][3] + bv);
        *(u32x2*)((char*)smem + byteo) = (u32x2){lo, hi};
      }
    }
    __syncthreads();
    const int b = bm0 >> 9, kt0 = (bm0 & 511) >> 6, h0 = bn0 >> 6;
    #pragma unroll
    for (int t4 = 0; t4 < 4; ++t4) {
      size_t base = ((size_t)(b * 8 + h0 + (t4 >> 1)) * 8 + kt0 + (t4 & 1)) * 4096;
      #pragma unroll
      for (int rnd = 0; rnd < 2; ++rnd) {
        int idx = rnd * 256 + tid;
        *(short8*)(vtg + base + idx * 8) = *(const short8*)&smem[t4 * 4096 + idx * 8];
      }
    }
  } else {
    #pragma unroll
    for (int j = 0; j < 4; ++j) {
      const int col = bn0 + wc*64 + j*16 + lr;
      const float bv = bias[col];
      #pragma unroll
      for (int i = 0; i < 4; ++i) {
        const int row0 = bm0 + wr*64 + i*16 + lg*4;
        #pragma unroll
        for (int q = 0; q < 4; ++q)
          st(&C[(size_t)(row0 + q) * HIDD + col], (acc[i][j][q] + bv) * oscale);
      }
    }
  }
}

// ---------------- k_mid: fill [0,1024) || QKV GEMM [1024,2560) (independent work) ----

__global__ __launch_bounds__(256, 3) void k_mid(
    const int* __restrict__ ei, const float* __restrict__ ea,
    const float* __restrict__ We, const float* __restrict__ be,
    int* __restrict__ rowcur, uint32_t* __restrict__ packed,
    const u16* __restrict__ A, const u16* __restrict__ Wt,
    const float* __restrict__ b0, const float* __restrict__ b1, const float* __restrict__ b2,
    u16* __restrict__ O0, u16* __restrict__ O1, u16* __restrict__ vtg) {
  __shared__ u16 smem[16384];   // 32KB (gemm); fill path carves 544B for We/be
  const int bid = blockIdx.x, t = threadIdx.x;
  if (bid < 1024) {
    float* w  = (float*)smem;        // 128 floats
    float* bb = (float*)smem + 128;  // 8 floats
    if (t < 128) w[t] = We[t];
    if (t < 8)   bb[t] = be[t];
    __syncthreads();
    int e = bid * 256 + t;
    int src = ei[e];
    int dl  = ei[NE + e] & (NPG - 1);
    const float* ap = ea + (size_t)e * 16;
    float a[16];
    #pragma unroll
    for (int i = 0; i < 16; i += 4) {
      float4v v = *(const float4v*)(ap + i);
      a[i]=v[0]; a[i+1]=v[1]; a[i+2]=v[2]; a[i+3]=v[3];
    }
    float acc[8];
    #pragma unroll
    for (int hh = 0; hh < 8; ++hh) acc[hh] = bb[hh];
    #pragma unroll
    for (int d = 0; d < 16; ++d)
      #pragma unroll
      for (int hh = 0; hh < 8; ++hh) acc[hh] += a[d] * w[d*8 + hh];
    int bin = src * 8 + (dl >> 6);
    int slot = atomicAdd(&rowcur[bin], 1);
    size_t base = (size_t)slot * 8;
    #pragma unroll
    for (int hh = 0; hh < 8; ++hh) {
      float m = fexp2(acc[hh] * 1.44269504089f);
      union { _Float16 hf; u16 us; } cv; cv.hf = (_Float16)m;
      packed[base + hh] = (uint32_t)(dl & 63) | ((uint32_t)cv.us << 16);
    }
  } else {
    const int idx = bid - 1024;
    const int z = idx >> 9, idl = idx & 511;
    const float c1 = 0.125f * 1.44269504089f;  // softmax scale folded into Q
    const u16* Bt = Wt + (size_t)z * HIDD * HIDD;
    if (z == 0)      gemm_body<u16, false>(smem, idl, A, Bt, b0, O0, nullptr, c1);
    else if (z == 1) gemm_body<u16, false>(smem, idl, A, Bt, b1, O1, nullptr, 1.0f);
    else             gemm_body<u16, true >(smem, idl, A, Bt, b2, nullptr, vtg, 1.0f);
  }
}

__global__ __launch_bounds__(256, 3) void k_gemm_out(
    const u16* __restrict__ A, const u16* __restrict__ Bt,
    const float* __restrict__ bias, float* __restrict__ C) {
  __shared__ u16 smem[16384];
  gemm_body<float, false>(smem, blockIdx.x + (blockIdx.y << 2), A, Bt, bias, C,
                          nullptr, 1.0f);
}

// ---------------- fused attention (R17 body, unchanged) ----------------

__global__ __launch_bounds__(256, 4) void k_attn(
    const u16* __restrict__ qb, const u16* __restrict__ kb, const u16* __restrict__ vtg,
    const uint32_t* __restrict__ packed, const uint32_t* __restrict__ rowse,
    u16* __restrict__ ab) {
  __shared__ u16 kl[4096];      // 8KB K tile [64 key][128B] swizzled
  __shared__ u16 vl[4096];      // 8KB V^T tile [64 d][128B] swizzled
  __shared__ u16 pl[4][2048];   // 16KB per-wave P tiles [32 row][64 key] swizzled
  const int tid = threadIdx.x, w = tid >> 6, l = tid & 63, lr = l & 15, lg = l >> 4;

  const int id = blockIdx.x;
  const int nid = (id & 7) * 128 + (id >> 3);   // XCD-contiguous (1024 % 8 == 0)
  const int q0 = (nid & 3) * 128;
  const int h  = (nid >> 2) & 7;
  const int b  = nid >> 5;
  const int bh = b * 8 + h;
  const int rbase = q0 + w * 32;                // wave's first q-row within graph
  u16* plw = &pl[w][0];
  const int pswz = (lr & 7) << 4;               // (g*16+lr)&7 == lr&7: group-invariant

  // Q fragments for both row groups
  bf16x8 qf[2][2];
  #pragma unroll
  for (int g = 0; g < 2; ++g) {
    const u16* qp = qb + (size_t)(b * NPG + rbase + g * 16 + lr) * HIDD + h * HD + lg * 8;
    qf[g][0] = ldfrag(qp);
    qf[g][1] = ldfrag(qp + 32);
  }

  auto stageK = [&](int kt) {
    #pragma unroll
    for (int rnd = 0; rnd < 2; ++rnd) {
      int o = rnd * 4096 + w * 1024 + l * 16;
      int key = o >> 7, db = o & 127;
      int col = db ^ ((key & 7) << 4);
      gl2lds16((const char*)kb + ((size_t)(b * NPG + kt * 64 + key) * HIDD + h * HD) * 2 + col,
               (char*)kl + o);
    }
  };
  auto stageV = [&](int kt) {
    #pragma unroll
    for (int rnd = 0; rnd < 2; ++rnd) {
      int o = rnd * 4096 + w * 1024 + l * 16;
      gl2lds16((const char*)vtg + ((size_t)(bh * 8 + kt)) * 8192 + o,
               (char*)vl + o);
    }
  };

  float rs[2] = {0.f, 0.f};
  f32x4 oacc[2][4];
  #pragma unroll
  for (int g = 0; g < 2; ++g)
    #pragma unroll
    for (int dt = 0; dt < 4; ++dt) oacc[g][dt] = (f32x4){0.f, 0.f, 0.f, 0.f};

  stageK(0); stageV(0);

  // per-lane edge row: group ge = lg&1, dst-parity class = lg>>1
  const int ge = lg & 1, ecls = lg >> 1;
  const int egrow = b * NPG + rbase + ge * 16 + lr;
  uint32_t ub = rowse[egrow * 8];
  int eE = (int)(ub >> 7), eA = eE - (int)(ub & 127u);

  for (int kt = 0; kt < 8; ++kt) {
    asm volatile("s_waitcnt vmcnt(0)" ::: "memory");   // K(kt), V(kt) landed
    __syncthreads();

    // prefetch next tile's packed bounds + this tile's first edge entry (fly under QK^T)
    uint32_t uN = (kt < 7) ? rowse[egrow * 8 + kt + 1] : 0;
    int s0c = (eA < eE) ? eA : 0;
    uint32_t u0 = packed[(size_t)s0c * 8 + h];

    // QK^T (swapped): s4[g][sub][e] = S[key = kt*64 + sub*16 + lg*4 + e][rbase+g*16+lr]
    f32x4 s4[2][4];
    __builtin_amdgcn_s_setprio(1);
    #pragma unroll
    for (int sub = 0; sub < 4; ++sub) {
      int key = sub * 16 + lr;
      bf16x8 kf0, kf1;
      {
        int db0 = ((lg * 8) * 2) ^ ((key & 7) << 4);
        int db1 = ((32 + lg * 8) * 2) ^ ((key & 7) << 4);
        kf0 = ldfrag(&kl[(key * 128 + db0) >> 1]);
        kf1 = ldfrag(&kl[(key * 128 + db1) >> 1]);
      }
      #pragma unroll
      for (int g = 0; g < 2; ++g) {
        s4[g][sub] = mfma16(kf0, qf[g][0], (f32x4){0.f, 0.f, 0.f, 0.f});
        s4[g][sub] = mfma16(kf1, qf[g][1], s4[g][sub]);
      }
    }
    __builtin_amdgcn_s_setprio(0);

    // p = exp2(S) (Q pre-scaled) -> per-wave LDS P tile; rowsums in regs
    #pragma unroll
    for (int g = 0; g < 2; ++g) {
      const int prow = g * 16 + lr;
      #pragma unroll
      for (int sub = 0; sub < 4; ++sub) {
        float p0 = fexp2(s4[g][sub][0]);
        float p1 = fexp2(s4[g][sub][1]);
        float p2 = fexp2(s4[g][sub][2]);
        float p3 = fexp2(s4[g][sub][3]);
        rs[g] += (p0 + p1) + (p2 + p3);
        uint32_t lo = pkbf(p0, p1);
        uint32_t hi = pkbf(p2, p3);
        *(u32x2*)((char*)plw + prow * 128 + ((sub * 32 + lg * 8) ^ pswz)) = (u32x2){lo, hi};
      }
    }
    asm volatile("s_waitcnt lgkmcnt(0)" ::: "memory");
    __builtin_amdgcn_sched_barrier(0);

    // edge multipliers: 2 lanes/row (dst parity classes), 1-ahead load pipeline
    {
      float delta = 0.f;
      const int re = ge * 16 + lr;
      uint32_t u = u0;
      for (int s = eA; s < eE; ++s) {
        uint32_t ucur = u;
        if (s + 1 < eE) u = packed[(size_t)(s + 1) * 8 + h];
        int dl = (int)(ucur & 63u);
        if ((dl & 1) == ecls) {
          union { u16 us; _Float16 hf; } cv; cv.us = (u16)(ucur >> 16);
          float mult = (float)cv.hf;
          int idx = (re * 128 + ((dl * 2) ^ pswz)) >> 1;
          float old = bf2f(plw[idx]);
          plw[idx] = f2bf(old * mult);
          delta += old * (mult - 1.0f);
        }
      }
      rs[0] += (ge == 0) ? delta : 0.f;
      rs[1] += (ge == 1) ? delta : 0.f;
    }
    asm volatile("s_waitcnt lgkmcnt(0)" ::: "memory");
    __builtin_amdgcn_sched_barrier(0);

    // PV: vf frags read once, used for both row groups
    __builtin_amdgcn_s_setprio(1);
    #pragma unroll
    for (int ks = 0; ks < 2; ++ks) {
      bf16x8 pa0 = ldfrag(&plw[(lr * 128 + ((ks * 64 + lg * 16) ^ pswz)) >> 1]);
      bf16x8 pa1 = ldfrag(&plw[((16 + lr) * 128 + ((ks * 64 + lg * 16) ^ pswz)) >> 1]);
      #pragma unroll
      for (int dt = 0; dt < 4; ++dt) {
        int d = dt * 16 + lr;
        bf16x8 vf = ldfrag(&vl[(d * 128 + ((ks * 64 + lg * 16) ^ ((d & 7) << 4))) >> 1]);
        oacc[0][dt] = mfma16(vf, pa0, oacc[0][dt]);
        oacc[1][dt] = mfma16(vf, pa1, oacc[1][dt]);
      }
    }
    __builtin_amdgcn_s_setprio(0);

    __syncthreads();   // all waves done reading kl/vl -> safe to restage
    if (kt < 7) { stageK(kt + 1); stageV(kt + 1); }
    eE = (int)(uN >> 7); eA = eE - (int)(uN & 127u);
  }

  // reduce rowsums across lg, normalize, store O (packed 8B per dt per group)
  #pragma unroll
  for (int g = 0; g < 2; ++g) {
    float tot = rs[g] + __shfl_xor(rs[g], 16, 64);
    tot += __shfl_xor(tot, 32, 64);
    float inv = 1.0f / tot;
    const size_t grow = (size_t)(b * NPG + rbase + g * 16 + lr);
    #pragma unroll
    for (int dt = 0; dt < 4; ++dt) {
      uint32_t lo = pkbf(oacc[g][dt][0] * inv, oacc[g][dt][1] * inv);
      uint32_t hi = pkbf(oacc[g][dt][2] * inv, oacc[g][dt][3] * inv);
      *(u32x2*)(ab + grow * HIDD + h * HD + dt * 16 + lg * 4) = (u32x2){lo, hi};
    }
  }
}

// ---------------- launch ----------------

extern "C" void kernel_launch(void* const* d_in, const int* in_sizes, int n_in,
                              void* d_out, int out_size, void* d_ws, size_t ws_size,
                              hipStream_t stream) {
  const float* x  = (const float*)d_in[0];
  const int*   ei = (const int*)d_in[2];
  const float* ea = (const float*)d_in[3];
  const float* Wq = (const float*)d_in[4];  const float* bq = (const float*)d_in[5];
  const float* Wk = (const float*)d_in[6];  const float* bk = (const float*)d_in[7];
  const float* Wv = (const float*)d_in[8];  const float* bv = (const float*)d_in[9];
  const float* Wo = (const float*)d_in[10]; const float* bo = (const float*)d_in[11];
  const float* We = (const float*)d_in[12]; const float* be = (const float*)d_in[13];

  char* ws = (char*)d_ws;
  const size_t MB = 1 << 20;
  u16*  xb  = (u16*)(ws);             // 16 MiB (aliased as ab after QKV GEMM)
  u16*  wt  = (u16*)(ws + 16*MB);     // 2 MiB
  u16*  qbp = (u16*)(ws + 18*MB);     // 16 MiB
  u16*  kbp = (u16*)(ws + 34*MB);     // 16 MiB
  u16*  vtg = (u16*)(ws + 50*MB);     // 16 MiB  V^T tiled/swizzled [bh][8][4096]
  uint32_t* packed = (uint32_t*)(ws + 66*MB);        // 8 MiB
  int*      rowstart2 = (int*)(ws + 74*MB);          // 512 KiB (scan -> fill cursor)
  uint32_t* rowse     = (uint32_t*)(ws + 74*MB + 640*1024);  // 512 KiB (end<<7|cnt)
  // counts2/gcur overlap the vtg region: dead before k_mid writes vtg
  int*  counts2 = (int*)(ws + 50*MB);                // 512 KiB
  int*  gcur    = (int*)(ws + 50*MB + 512*1024);     // 4 B
  u16*  ab = xb;

  (void)hipMemsetAsync(counts2, 0, 512 * 1024 + 64, stream);  // counts2 + gcur

  k_prep<<<dim3(6144), 256, 0, stream>>>(x, xb, Wq, Wk, Wv, Wo, wt, ei, counts2);
  k_scan_u<<<dim3(512), 256, 0, stream>>>(counts2, rowstart2, rowse, gcur);

  k_mid<<<dim3(2560), 256, 0, stream>>>(ei, ea, We, be, rowstart2, packed,
                                        xb, wt, bq, bk, bv, qbp, kbp, vtg);

  k_attn<<<dim3(1024), 256, 0, stream>>>(qbp, kbp, vtg, packed, rowse, ab);

  k_gemm_out<<<dim3(HIDD / 128, NNODE / 128, 1), 256, 0, stream>>>(
      ab, wt + (size_t)3 * HIDD * HIDD, bo, (float*)d_out);
}